// Round 1
// baseline (1304.023 us; speedup 1.0000x reference)
//
#include <hip/hip_runtime.h>
#include <math.h>

#define T_LEN 2048
#define BATCH 2
#define EMB 1024
#define NHEAD 16
#define HDIM 64
#define BH (BATCH*NHEAD)          // 32
#define MROWS (T_LEN*BATCH)       // 4096
#define SCALING 0.125f            // 1/sqrt(64)
#define HEADBUF ((size_t)BH*T_LEN*HDIM)   // 4,194,304 floats

// ---------------------------------------------------------------------------
// Kernel 1: fused QKV in-projection.  out[m][n] = X[m][:] . W[which*E + n][:]
// X viewed as (T*B, E); result written head-major: [(b*H+h)*T + t][dd]
// grid: (MROWS/64, EMB/64, 3), block 256
// ---------------------------------------------------------------------------
__global__ __launch_bounds__(256) void proj_kernel(
    const float* __restrict__ Xq, const float* __restrict__ Xk,
    const float* __restrict__ Xv, const float* __restrict__ W,
    const float* __restrict__ bias, float* __restrict__ qkv_ws)
{
    const int which = blockIdx.z;
    const float* __restrict__ X = (which == 0) ? Xq : (which == 1) ? Xk : Xv;
    const int mBase = blockIdx.x * 64;
    const int nBase = blockIdx.y * 64;

    __shared__ float Xst[16][68];   // [kk][m] transposed
    __shared__ float Wst[16][68];   // [kk][n] transposed

    const int tid = threadIdx.x;
    const int tx = tid & 15, ty = tid >> 4;
    const int c = tid & 15;         // k-col within tile
    const int r0 = tid >> 4;        // row base

    float acc[4][4] = {};

    for (int kb = 0; kb < EMB; kb += 16) {
        __syncthreads();
        #pragma unroll
        for (int it = 0; it < 4; ++it) {
            int r = r0 + 16 * it;
            Xst[c][r] = X[(size_t)(mBase + r) * EMB + kb + c];
            Wst[c][r] = W[(size_t)(which * EMB + nBase + r) * EMB + kb + c];
        }
        __syncthreads();
        #pragma unroll
        for (int kk = 0; kk < 16; ++kk) {
            float4 a4 = *(const float4*)&Xst[kk][ty * 4];
            float4 b4 = *(const float4*)&Wst[kk][tx * 4];
            float av[4] = {a4.x, a4.y, a4.z, a4.w};
            float bv[4] = {b4.x, b4.y, b4.z, b4.w};
            #pragma unroll
            for (int i = 0; i < 4; ++i)
                #pragma unroll
                for (int j = 0; j < 4; ++j)
                    acc[i][j] += av[i] * bv[j];
        }
    }

    float* __restrict__ dst = qkv_ws + (size_t)which * HEADBUF;
    const int h = nBase >> 6;       // head index (tile width == HDIM)
    #pragma unroll
    for (int i = 0; i < 4; ++i) {
        int m = mBase + ty * 4 + i;
        int t = m / BATCH, b = m % BATCH;
        float o[4];
        #pragma unroll
        for (int j = 0; j < 4; ++j) {
            o[j] = acc[i][j] + bias[which * EMB + nBase + tx * 4 + j];
            if (which == 0) o[j] *= SCALING;
        }
        float4 o4 = make_float4(o[0], o[1], o[2], o[3]);
        *(float4*)&dst[((size_t)(b * NHEAD + h) * T_LEN + t) * HDIM + tx * 4] = o4;
    }
}

// ---------------------------------------------------------------------------
// Kernel 2: flash attention per (head, 64-query tile). Online softmax.
// Writes head_out (unprojected), and per-row running max m / denom l.
// grid: (T_LEN/64, BH), block 256
// ---------------------------------------------------------------------------
__global__ __launch_bounds__(256) void flash_kernel(
    const float* __restrict__ q_ws, const float* __restrict__ k_ws,
    const float* __restrict__ v_ws, float* __restrict__ ho,
    float* __restrict__ m_ws, float* __restrict__ l_ws)
{
    const int qt = blockIdx.x;      // 0..31
    const int hb = blockIdx.y;      // 0..31

    __shared__ float qst[64][68];   // [dd][qi]
    __shared__ float kst[64][68];   // [dd][sj]
    __shared__ float vs [64][68];   // [sj][dd]
    __shared__ float ps [64][68];   // [qi][sj]

    const int tid = threadIdx.x;
    const int tx = tid & 15, ty = tid >> 4;
    const int r = tid >> 4;
    const int c4 = (tid & 15) * 4;

    // load q tile transposed
    {
        const float* __restrict__ qsrc = q_ws + ((size_t)hb * T_LEN + qt * 64) * HDIM;
        #pragma unroll
        for (int it = 0; it < 4; ++it) {
            int row = r + 16 * it;
            float4 v4 = *(const float4*)&qsrc[row * HDIM + c4];
            qst[c4 + 0][row] = v4.x; qst[c4 + 1][row] = v4.y;
            qst[c4 + 2][row] = v4.z; qst[c4 + 3][row] = v4.w;
        }
    }

    float m_r[4], l_r[4], o_acc[4][4] = {};
    #pragma unroll
    for (int i = 0; i < 4; ++i) { m_r[i] = -INFINITY; l_r[i] = 0.f; }

    for (int st = 0; st < T_LEN / 64; ++st) {
        __syncthreads();   // previous PV done before overwriting kst/vs
        const float* __restrict__ ksrc = k_ws + ((size_t)hb * T_LEN + st * 64) * HDIM;
        const float* __restrict__ vsrc = v_ws + ((size_t)hb * T_LEN + st * 64) * HDIM;
        #pragma unroll
        for (int it = 0; it < 4; ++it) {
            int row = r + 16 * it;
            float4 kv = *(const float4*)&ksrc[row * HDIM + c4];
            kst[c4 + 0][row] = kv.x; kst[c4 + 1][row] = kv.y;
            kst[c4 + 2][row] = kv.z; kst[c4 + 3][row] = kv.w;
            *(float4*)&vs[row][c4] = *(const float4*)&vsrc[row * HDIM + c4];
        }
        __syncthreads();

        // scores: sc[qi][sj] = sum_dd q[qi][dd] * k[sj][dd]
        float sc[4][4] = {};
        #pragma unroll 8
        for (int dd = 0; dd < 64; ++dd) {
            float4 a4 = *(const float4*)&qst[dd][ty * 4];
            float4 b4 = *(const float4*)&kst[dd][tx * 4];
            float av[4] = {a4.x, a4.y, a4.z, a4.w};
            float bv[4] = {b4.x, b4.y, b4.z, b4.w};
            #pragma unroll
            for (int i = 0; i < 4; ++i)
                #pragma unroll
                for (int j = 0; j < 4; ++j)
                    sc[i][j] += av[i] * bv[j];
        }

        // online softmax update (rows replicated across the 16 tx lanes)
        #pragma unroll
        for (int i = 0; i < 4; ++i) {
            float tmax = fmaxf(fmaxf(sc[i][0], sc[i][1]), fmaxf(sc[i][2], sc[i][3]));
            #pragma unroll
            for (int w = 1; w < 16; w <<= 1) tmax = fmaxf(tmax, __shfl_xor(tmax, w));
            float mnew  = fmaxf(m_r[i], tmax);
            float scale = expf(m_r[i] - mnew);
            float pf[4], psum = 0.f;
            #pragma unroll
            for (int j = 0; j < 4; ++j) { pf[j] = expf(sc[i][j] - mnew); psum += pf[j]; }
            #pragma unroll
            for (int w = 1; w < 16; w <<= 1) psum += __shfl_xor(psum, w);
            l_r[i] = l_r[i] * scale + psum;
            m_r[i] = mnew;
            #pragma unroll
            for (int j = 0; j < 4; ++j) o_acc[i][j] *= scale;
            *(float4*)&ps[ty * 4 + i][tx * 4] = make_float4(pf[0], pf[1], pf[2], pf[3]);
        }
        __syncthreads();   // ps visible

        // PV: o[qi][dd] += p[qi][sj] * v[sj][dd]
        #pragma unroll 4
        for (int sj = 0; sj < 64; ++sj) {
            float4 v4 = *(const float4*)&vs[sj][tx * 4];
            float vv[4] = {v4.x, v4.y, v4.z, v4.w};
            #pragma unroll
            for (int i = 0; i < 4; ++i) {
                float p = ps[ty * 4 + i][sj];
                #pragma unroll
                for (int j = 0; j < 4; ++j) o_acc[i][j] += p * vv[j];
            }
        }
    }

    // epilogue
    #pragma unroll
    for (int i = 0; i < 4; ++i) {
        int row = qt * 64 + ty * 4 + i;
        float inv = 1.0f / l_r[i];
        float4 o4 = make_float4(o_acc[i][0] * inv, o_acc[i][1] * inv,
                                o_acc[i][2] * inv, o_acc[i][3] * inv);
        *(float4*)&ho[((size_t)hb * T_LEN + row) * HDIM + tx * 4] = o4;
        if (tx == 0) {
            m_ws[(size_t)hb * T_LEN + row] = m_r[i];
            l_ws[(size_t)hb * T_LEN + row] = l_r[i];
        }
    }
}

// ---------------------------------------------------------------------------
// Kernel 3: attn_avg. For a fixed (b, q-tile, s-tile), recompute scores for
// all 16 heads, probs via stored m/l, accumulate in registers, write once.
// grid: (S/64, T/64, B), block 256
// ---------------------------------------------------------------------------
__global__ __launch_bounds__(256) void avg_kernel(
    const float* __restrict__ q_ws, const float* __restrict__ k_ws,
    const float* __restrict__ m_ws, const float* __restrict__ l_ws,
    float* __restrict__ attn_avg)
{
    const int st = blockIdx.x;
    const int qt = blockIdx.y;
    const int b  = blockIdx.z;

    __shared__ float qst[64][68];
    __shared__ float kst[64][68];

    const int tid = threadIdx.x;
    const int tx = tid & 15, ty = tid >> 4;
    const int r = tid >> 4;
    const int c4 = (tid & 15) * 4;

    float acc[4][4] = {};

    for (int h = 0; h < NHEAD; ++h) {
        int hb = b * NHEAD + h;
        __syncthreads();
        const float* __restrict__ qsrc = q_ws + ((size_t)hb * T_LEN + qt * 64) * HDIM;
        const float* __restrict__ ksrc = k_ws + ((size_t)hb * T_LEN + st * 64) * HDIM;
        #pragma unroll
        for (int it = 0; it < 4; ++it) {
            int row = r + 16 * it;
            float4 qv = *(const float4*)&qsrc[row * HDIM + c4];
            qst[c4 + 0][row] = qv.x; qst[c4 + 1][row] = qv.y;
            qst[c4 + 2][row] = qv.z; qst[c4 + 3][row] = qv.w;
            float4 kv = *(const float4*)&ksrc[row * HDIM + c4];
            kst[c4 + 0][row] = kv.x; kst[c4 + 1][row] = kv.y;
            kst[c4 + 2][row] = kv.z; kst[c4 + 3][row] = kv.w;
        }
        __syncthreads();

        float sc[4][4] = {};
        #pragma unroll 8
        for (int dd = 0; dd < 64; ++dd) {
            float4 a4 = *(const float4*)&qst[dd][ty * 4];
            float4 b4 = *(const float4*)&kst[dd][tx * 4];
            float av[4] = {a4.x, a4.y, a4.z, a4.w};
            float bv[4] = {b4.x, b4.y, b4.z, b4.w};
            #pragma unroll
            for (int i = 0; i < 4; ++i)
                #pragma unroll
                for (int j = 0; j < 4; ++j)
                    sc[i][j] += av[i] * bv[j];
        }

        #pragma unroll
        for (int i = 0; i < 4; ++i) {
            int row = qt * 64 + ty * 4 + i;
            float mm  = m_ws[(size_t)hb * T_LEN + row];
            float inv = 1.0f / l_ws[(size_t)hb * T_LEN + row];
            #pragma unroll
            for (int j = 0; j < 4; ++j)
                acc[i][j] += expf(sc[i][j] - mm) * inv;
        }
    }

    const float invH = 1.0f / (float)NHEAD;
    #pragma unroll
    for (int i = 0; i < 4; ++i) {
        int row = qt * 64 + ty * 4 + i;
        float4 o4 = make_float4(acc[i][0] * invH, acc[i][1] * invH,
                                acc[i][2] * invH, acc[i][3] * invH);
        *(float4*)&attn_avg[((size_t)b * T_LEN + row) * T_LEN + st * 64 + tx * 4] = o4;
    }
}

// ---------------------------------------------------------------------------
// Kernel 4: out-projection. out[m][n] = ho_gathered[m][:] . Wo[n][:] + bo[n]
// grid: (MROWS/64, EMB/64), block 256
// ---------------------------------------------------------------------------
__global__ __launch_bounds__(256) void outproj_kernel(
    const float* __restrict__ ho, const float* __restrict__ Wo,
    const float* __restrict__ bo, float* __restrict__ out)
{
    const int mBase = blockIdx.x * 64;
    const int nBase = blockIdx.y * 64;

    __shared__ float Xst[16][68];
    __shared__ float Wst[16][68];

    const int tid = threadIdx.x;
    const int tx = tid & 15, ty = tid >> 4;
    const int c = tid & 15;
    const int r0 = tid >> 4;

    float acc[4][4] = {};

    for (int kb = 0; kb < EMB; kb += 16) {
        __syncthreads();
        #pragma unroll
        for (int it = 0; it < 4; ++it) {
            int rr = r0 + 16 * it;
            int m = mBase + rr;
            int e = kb + c;
            int t = m / BATCH, b = m % BATCH;
            int h = e >> 6, dd = e & 63;
            Xst[c][rr] = ho[((size_t)(b * NHEAD + h) * T_LEN + t) * HDIM + dd];
            Wst[c][rr] = Wo[(size_t)(nBase + rr) * EMB + e];
        }
        __syncthreads();
        #pragma unroll
        for (int kk = 0; kk < 16; ++kk) {
            float4 a4 = *(const float4*)&Xst[kk][ty * 4];
            float4 b4 = *(const float4*)&Wst[kk][tx * 4];
            float av[4] = {a4.x, a4.y, a4.z, a4.w};
            float bv[4] = {b4.x, b4.y, b4.z, b4.w};
            #pragma unroll
            for (int i = 0; i < 4; ++i)
                #pragma unroll
                for (int j = 0; j < 4; ++j)
                    acc[i][j] += av[i] * bv[j];
        }
    }

    #pragma unroll
    for (int i = 0; i < 4; ++i) {
        int m = mBase + ty * 4 + i;
        float o[4];
        #pragma unroll
        for (int j = 0; j < 4; ++j)
            o[j] = acc[i][j] + bo[nBase + tx * 4 + j];
        float4 o4 = make_float4(o[0], o[1], o[2], o[3]);
        *(float4*)&out[(size_t)m * EMB + nBase + tx * 4] = o4;
    }
}

// ---------------------------------------------------------------------------
extern "C" void kernel_launch(void* const* d_in, const int* in_sizes, int n_in,
                              void* d_out, int out_size, void* d_ws, size_t ws_size,
                              hipStream_t stream)
{
    const float* query = (const float*)d_in[0];
    const float* key   = (const float*)d_in[1];
    const float* value = (const float*)d_in[2];
    const float* ipw   = (const float*)d_in[3];
    const float* ipb   = (const float*)d_in[4];
    const float* opw   = (const float*)d_in[5];
    const float* opb   = (const float*)d_in[6];

    float* ws  = (float*)d_ws;
    float* q   = ws;                    // HEADBUF floats
    float* k   = ws + HEADBUF;
    float* v   = ws + 2 * HEADBUF;
    float* ho  = ws + 3 * HEADBUF;
    float* mws = ws + 4 * HEADBUF;      // BH*T_LEN floats
    float* lws = mws + (size_t)BH * T_LEN;

    float* out      = (float*)d_out;
    float* attn_avg = out + (size_t)MROWS * EMB;

    proj_kernel   <<<dim3(MROWS / 64, EMB / 64, 3), 256, 0, stream>>>(query, key, value, ipw, ipb, ws);
    flash_kernel  <<<dim3(T_LEN / 64, BH),          256, 0, stream>>>(q, k, v, ho, mws, lws);
    avg_kernel    <<<dim3(T_LEN / 64, T_LEN / 64, BATCH), 256, 0, stream>>>(q, k, mws, lws, attn_avg);
    outproj_kernel<<<dim3(MROWS / 64, EMB / 64),    256, 0, stream>>>(ho, opw, opb, out);
}

// Round 2
// 389.411 us; speedup vs baseline: 3.3487x; 3.3487x over previous
//
#include <hip/hip_runtime.h>
#include <math.h>

#define T_LEN 2048
#define BATCH 2
#define EMB 1024
#define NHEAD 16
#define HDIM 64
#define BH (BATCH*NHEAD)          // 32
#define MROWS (T_LEN*BATCH)       // 4096
#define SCALING 0.125f            // 1/sqrt(64)
#define HEADBUF ((size_t)BH*T_LEN*HDIM)   // 4,194,304 elements

typedef __attribute__((ext_vector_type(8))) short bf16x8;
typedef __attribute__((ext_vector_type(4))) float f32x4;

#define MFMA16(a,b,c) __builtin_amdgcn_mfma_f32_16x16x32_bf16(a,b,c,0,0,0)

__device__ __forceinline__ short f2bf(float f) {
    union { float f; unsigned u; } v; v.f = f;
    unsigned r = (v.u + 0x7FFFu + ((v.u >> 16) & 1u)) >> 16;   // RNE
    return (short)(unsigned short)r;
}

// ---------------------------------------------------------------------------
// Kernel 1: fused QKV in-projection, bf16 MFMA.
// C[m][n] = X[m][:] . W[n][:] (+bias), n in [0,3072); which = n>>10 selects
// X in {query,key,value} and the destination head-major bf16 buffer.
// 128x128 tile, BK=64, 4 waves each owning a 64x64 quadrant.
// grid: (MROWS/128=32, 3*EMB/128=24), block 256
// ---------------------------------------------------------------------------
__global__ __launch_bounds__(256) void inproj_gemm(
    const float* __restrict__ Xq, const float* __restrict__ Xk,
    const float* __restrict__ Xv, const float* __restrict__ W,
    const float* __restrict__ bias,
    short* __restrict__ qb, short* __restrict__ kbuf, short* __restrict__ vbuf)
{
    const int mBase = blockIdx.x * 128;
    const int nBase = blockIdx.y * 128;
    const int which = nBase >> 10;
    const float* __restrict__ X = (which == 0) ? Xq : (which == 1) ? Xk : Xv;
    short* __restrict__ dst = (which == 0) ? qb : (which == 1) ? kbuf : vbuf;

    __shared__ short Ast[128][72];   // pad 64->72: stride 144B, conflict-free
    __shared__ short Bst[128][72];

    const int tid  = threadIdx.x;
    const int lane = tid & 63;
    const int w    = tid >> 6;
    const int wr   = w >> 1, wc = w & 1;
    const int lr   = lane & 15, lg = lane >> 4;

    f32x4 acc[4][4] = {};

    for (int kb = 0; kb < EMB; kb += 64) {
        __syncthreads();
        #pragma unroll
        for (int it = 0; it < 4; ++it) {
            int c = tid + 256 * it;          // 0..1023
            int r = c >> 3, kc = c & 7;
            const float* sa = &X[(size_t)(mBase + r) * EMB + kb + kc * 8];
            float4 f0 = *(const float4*)sa;
            float4 f1 = *(const float4*)(sa + 4);
            bf16x8 av;
            av[0]=f2bf(f0.x); av[1]=f2bf(f0.y); av[2]=f2bf(f0.z); av[3]=f2bf(f0.w);
            av[4]=f2bf(f1.x); av[5]=f2bf(f1.y); av[6]=f2bf(f1.z); av[7]=f2bf(f1.w);
            *(bf16x8*)&Ast[r][kc * 8] = av;
            const float* sb = &W[(size_t)(nBase + r) * EMB + kb + kc * 8];
            float4 g0 = *(const float4*)sb;
            float4 g1 = *(const float4*)(sb + 4);
            bf16x8 bv;
            bv[0]=f2bf(g0.x); bv[1]=f2bf(g0.y); bv[2]=f2bf(g0.z); bv[3]=f2bf(g0.w);
            bv[4]=f2bf(g1.x); bv[5]=f2bf(g1.y); bv[6]=f2bf(g1.z); bv[7]=f2bf(g1.w);
            *(bf16x8*)&Bst[r][kc * 8] = bv;
        }
        __syncthreads();
        #pragma unroll
        for (int ks = 0; ks < 2; ++ks) {
            bf16x8 af[4], bfr[4];
            #pragma unroll
            for (int rg = 0; rg < 4; ++rg)
                af[rg] = *(const bf16x8*)&Ast[wr * 64 + rg * 16 + lr][ks * 32 + lg * 8];
            #pragma unroll
            for (int cg = 0; cg < 4; ++cg)
                bfr[cg] = *(const bf16x8*)&Bst[wc * 64 + cg * 16 + lr][ks * 32 + lg * 8];
            #pragma unroll
            for (int rg = 0; rg < 4; ++rg)
                #pragma unroll
                for (int cg = 0; cg < 4; ++cg)
                    acc[rg][cg] = MFMA16(af[rg], bfr[cg], acc[rg][cg]);
        }
    }

    // epilogue: bias (+scaling for q), write head-major bf16
    #pragma unroll
    for (int rg = 0; rg < 4; ++rg) {
        #pragma unroll
        for (int cg = 0; cg < 4; ++cg) {
            int n  = nBase + wc * 64 + cg * 16 + lr;
            int e  = n & 1023;
            int h  = e >> 6, dd = e & 63;
            float bs = bias[n];
            #pragma unroll
            for (int ri = 0; ri < 4; ++ri) {
                int m = mBase + wr * 64 + rg * 16 + lg * 4 + ri;
                int t = m >> 1, b = m & 1;
                float val = acc[rg][cg][ri] + bs;
                if (which == 0) val *= SCALING;
                dst[((size_t)(b * NHEAD + h) * T_LEN + t) * HDIM + dd] = f2bf(val);
            }
        }
    }
}

// ---------------------------------------------------------------------------
// Kernel 2: flash attention, bf16 MFMA. Block = (qt, head) = 64 q-rows,
// 4 waves each owning 16 q-rows. S-tile 64. K row-major LDS (acts as B^T),
// V transposed into LDS on stage so PV B-frags are contiguous b128 reads.
// grid: (T_LEN/64=32, BH=32), block 256
// ---------------------------------------------------------------------------
__global__ __launch_bounds__(256) void flash_kernel(
    const short* __restrict__ qb, const short* __restrict__ kbuf,
    const short* __restrict__ vbuf, float* __restrict__ ho,
    float* __restrict__ mws, float* __restrict__ lws)
{
    const int qt = blockIdx.x;
    const int hb = blockIdx.y;

    __shared__ short Kst[64][72];   // [s][d]
    __shared__ short VT [64][72];   // [d][s]
    __shared__ short Pst[64][72];   // [q][s], wave-private 16-row slices

    const int tid  = threadIdx.x;
    const int lane = tid & 63;
    const int w    = tid >> 6;
    const int lr   = lane & 15, lg = lane >> 4;

    // Q fragments (16 rows per wave), loaded once
    bf16x8 qa0, qa1;
    {
        const short* qsrc = qb + ((size_t)hb * T_LEN + qt * 64 + w * 16 + lr) * HDIM;
        qa0 = *(const bf16x8*)(qsrc + lg * 8);
        qa1 = *(const bf16x8*)(qsrc + 32 + lg * 8);
    }

    float m_r[4], l_r[4];
    f32x4 o_acc[4] = {};            // [dsub]; component = q-row reg
    #pragma unroll
    for (int i = 0; i < 4; ++i) { m_r[i] = -INFINITY; l_r[i] = 0.f; }

    for (int st = 0; st < T_LEN / 64; ++st) {
        __syncthreads();            // prior PV reads of Kst/VT complete
        // stage K (row-major)
        #pragma unroll
        for (int it = 0; it < 2; ++it) {
            int c = tid + 256 * it;
            int r = c >> 3, kc = c & 7;
            *(bf16x8*)&Kst[r][kc * 8] =
                *(const bf16x8*)(kbuf + ((size_t)hb * T_LEN + st * 64 + r) * HDIM + kc * 8);
        }
        // stage V transposed: thread -> rows (s0,s0+1) x 8 d-cols, packed u32 writes
        {
            int dc = tid & 7;
            int s0 = (tid >> 3) * 2;
            const short* v0 = vbuf + ((size_t)hb * T_LEN + st * 64 + s0) * HDIM + dc * 8;
            bf16x8 va = *(const bf16x8*)v0;
            bf16x8 vb2 = *(const bf16x8*)(v0 + HDIM);
            #pragma unroll
            for (int j = 0; j < 8; ++j) {
                unsigned pk = ((unsigned)(unsigned short)va[j]) |
                              (((unsigned)(unsigned short)vb2[j]) << 16);
                *(unsigned*)&VT[dc * 8 + j][s0] = pk;
            }
        }
        __syncthreads();

        // QK^T: sc[sg] covers s-cols sg*16+lr, q-rows lg*4+ri
        f32x4 sc[4] = {};
        #pragma unroll
        for (int sg = 0; sg < 4; ++sg) {
            bf16x8 kf0 = *(const bf16x8*)&Kst[sg * 16 + lr][lg * 8];
            bf16x8 kf1 = *(const bf16x8*)&Kst[sg * 16 + lr][32 + lg * 8];
            sc[sg] = MFMA16(qa0, kf0, sc[sg]);
            sc[sg] = MFMA16(qa1, kf1, sc[sg]);
        }

        // online softmax (per q-row; rows live in reg index, cols across lr lanes)
        float pv[4][4], scl[4];
        #pragma unroll
        for (int ri = 0; ri < 4; ++ri) {
            float mx = fmaxf(fmaxf(sc[0][ri], sc[1][ri]), fmaxf(sc[2][ri], sc[3][ri]));
            #pragma unroll
            for (int msk = 1; msk < 16; msk <<= 1) mx = fmaxf(mx, __shfl_xor(mx, msk));
            float mnew = fmaxf(m_r[ri], mx);
            scl[ri] = __expf(m_r[ri] - mnew);
            float psum = 0.f;
            #pragma unroll
            for (int sg = 0; sg < 4; ++sg) {
                float p = __expf(sc[sg][ri] - mnew);
                pv[sg][ri] = p; psum += p;
            }
            #pragma unroll
            for (int msk = 1; msk < 16; msk <<= 1) psum += __shfl_xor(psum, msk);
            l_r[ri] = l_r[ri] * scl[ri] + psum;
            m_r[ri] = mnew;
        }
        #pragma unroll
        for (int dsub = 0; dsub < 4; ++dsub)
            #pragma unroll
            for (int ri = 0; ri < 4; ++ri)
                o_acc[dsub][ri] *= scl[ri];

        // P -> bf16 -> wave-private LDS rows
        #pragma unroll
        for (int sg = 0; sg < 4; ++sg)
            #pragma unroll
            for (int ri = 0; ri < 4; ++ri)
                Pst[w * 16 + lg * 4 + ri][sg * 16 + lr] = f2bf(pv[sg][ri]);

        // PV: O[q][d] += P[q][s] * V[s][d]
        #pragma unroll
        for (int ks = 0; ks < 2; ++ks) {
            bf16x8 pa = *(const bf16x8*)&Pst[w * 16 + lr][ks * 32 + lg * 8];
            #pragma unroll
            for (int dsub = 0; dsub < 4; ++dsub) {
                bf16x8 vf = *(const bf16x8*)&VT[dsub * 16 + lr][ks * 32 + lg * 8];
                o_acc[dsub] = MFMA16(pa, vf, o_acc[dsub]);
            }
        }
    }

    // epilogue
    #pragma unroll
    for (int ri = 0; ri < 4; ++ri) {
        int row = qt * 64 + w * 16 + lg * 4 + ri;
        float inv = 1.0f / l_r[ri];
        #pragma unroll
        for (int dsub = 0; dsub < 4; ++dsub)
            ho[((size_t)hb * T_LEN + row) * HDIM + dsub * 16 + lr] = o_acc[dsub][ri] * inv;
        if (lr == 0) {
            mws[(size_t)hb * T_LEN + row] = m_r[ri];
            lws[(size_t)hb * T_LEN + row] = l_r[ri];
        }
    }
}

// ---------------------------------------------------------------------------
// Kernel 3: attn_avg via MFMA score recompute (bit-identical to flash scores),
// probs from stored m/l, accumulate 16 heads in registers.
// grid: (32 st, 32 qt, 2 b), block 256
// ---------------------------------------------------------------------------
__global__ __launch_bounds__(256) void avg_kernel(
    const short* __restrict__ qb, const short* __restrict__ kbuf,
    const float* __restrict__ mws, const float* __restrict__ lws,
    float* __restrict__ attn_avg)
{
    const int st = blockIdx.x;
    const int qt = blockIdx.y;
    const int b  = blockIdx.z;

    __shared__ short Kst[64][72];

    const int tid  = threadIdx.x;
    const int lane = tid & 63;
    const int w    = tid >> 6;
    const int lr   = lane & 15, lg = lane >> 4;

    f32x4 acc[4] = {};   // [sg]; component = q-row reg

    for (int h = 0; h < NHEAD; ++h) {
        const int hb = b * NHEAD + h;
        __syncthreads();
        #pragma unroll
        for (int it = 0; it < 2; ++it) {
            int c = tid + 256 * it;
            int r = c >> 3, kc = c & 7;
            *(bf16x8*)&Kst[r][kc * 8] =
                *(const bf16x8*)(kbuf + ((size_t)hb * T_LEN + st * 64 + r) * HDIM + kc * 8);
        }
        __syncthreads();

        const short* qsrc = qb + ((size_t)hb * T_LEN + qt * 64 + w * 16 + lr) * HDIM;
        bf16x8 qa0 = *(const bf16x8*)(qsrc + lg * 8);
        bf16x8 qa1 = *(const bf16x8*)(qsrc + 32 + lg * 8);

        f32x4 sc[4] = {};
        #pragma unroll
        for (int sg = 0; sg < 4; ++sg) {
            bf16x8 kf0 = *(const bf16x8*)&Kst[sg * 16 + lr][lg * 8];
            bf16x8 kf1 = *(const bf16x8*)&Kst[sg * 16 + lr][32 + lg * 8];
            sc[sg] = MFMA16(qa0, kf0, sc[sg]);
            sc[sg] = MFMA16(qa1, kf1, sc[sg]);
        }

        #pragma unroll
        for (int ri = 0; ri < 4; ++ri) {
            int row = qt * 64 + w * 16 + lg * 4 + ri;
            float mm  = mws[(size_t)hb * T_LEN + row];
            float inv = 1.0f / lws[(size_t)hb * T_LEN + row];
            #pragma unroll
            for (int sg = 0; sg < 4; ++sg)
                acc[sg][ri] += __expf(sc[sg][ri] - mm) * inv;
        }
    }

    const float invH = 1.0f / (float)NHEAD;
    #pragma unroll
    for (int ri = 0; ri < 4; ++ri) {
        int row = qt * 64 + w * 16 + lg * 4 + ri;
        #pragma unroll
        for (int sg = 0; sg < 4; ++sg)
            attn_avg[((size_t)b * T_LEN + row) * T_LEN + st * 64 + sg * 16 + lr] =
                acc[sg][ri] * invH;
    }
}

// ---------------------------------------------------------------------------
// Kernel 4: out-projection, fp32 (precision reserve for output 0).
// grid: (MROWS/64, EMB/64), block 256
// ---------------------------------------------------------------------------
__global__ __launch_bounds__(256) void outproj_kernel(
    const float* __restrict__ ho, const float* __restrict__ Wo,
    const float* __restrict__ bo, float* __restrict__ out)
{
    const int mBase = blockIdx.x * 64;
    const int nBase = blockIdx.y * 64;

    __shared__ float Xst[16][68];
    __shared__ float Wst[16][68];

    const int tid = threadIdx.x;
    const int tx = tid & 15, ty = tid >> 4;
    const int c = tid & 15;
    const int r0 = tid >> 4;

    float acc[4][4] = {};

    for (int kb = 0; kb < EMB; kb += 16) {
        __syncthreads();
        #pragma unroll
        for (int it = 0; it < 4; ++it) {
            int rr = r0 + 16 * it;
            int m = mBase + rr;
            int e = kb + c;
            int t = m >> 1, b = m & 1;
            int h = e >> 6, dd = e & 63;
            Xst[c][rr] = ho[((size_t)(b * NHEAD + h) * T_LEN + t) * HDIM + dd];
            Wst[c][rr] = Wo[(size_t)(nBase + rr) * EMB + e];
        }
        __syncthreads();
        #pragma unroll
        for (int kk = 0; kk < 16; ++kk) {
            float4 a4 = *(const float4*)&Xst[kk][ty * 4];
            float4 b4 = *(const float4*)&Wst[kk][tx * 4];
            float av[4] = {a4.x, a4.y, a4.z, a4.w};
            float bv[4] = {b4.x, b4.y, b4.z, b4.w};
            #pragma unroll
            for (int i = 0; i < 4; ++i)
                #pragma unroll
                for (int j = 0; j < 4; ++j)
                    acc[i][j] += av[i] * bv[j];
        }
    }

    #pragma unroll
    for (int i = 0; i < 4; ++i) {
        int m = mBase + ty * 4 + i;
        float o[4];
        #pragma unroll
        for (int j = 0; j < 4; ++j)
            o[j] = acc[i][j] + bo[nBase + tx * 4 + j];
        float4 o4 = make_float4(o[0], o[1], o[2], o[3]);
        *(float4*)&out[(size_t)m * EMB + nBase + tx * 4] = o4;
    }
}

// ---------------------------------------------------------------------------
extern "C" void kernel_launch(void* const* d_in, const int* in_sizes, int n_in,
                              void* d_out, int out_size, void* d_ws, size_t ws_size,
                              hipStream_t stream)
{
    const float* query = (const float*)d_in[0];
    const float* key   = (const float*)d_in[1];
    const float* value = (const float*)d_in[2];
    const float* ipw   = (const float*)d_in[3];
    const float* ipb   = (const float*)d_in[4];
    const float* opw   = (const float*)d_in[5];
    const float* opb   = (const float*)d_in[6];

    short* qb  = (short*)d_ws;                 // bf16, HEADBUF each
    short* kb  = qb + HEADBUF;
    short* vb  = kb + HEADBUF;
    float* ho  = (float*)(vb + HEADBUF);       // fp32, HEADBUF
    float* mws = ho + HEADBUF;                 // BH*T_LEN
    float* lws = mws + (size_t)BH * T_LEN;

    float* out      = (float*)d_out;
    float* attn_avg = out + (size_t)MROWS * EMB;

    inproj_gemm  <<<dim3(MROWS / 128, 3 * EMB / 128), 256, 0, stream>>>(
        query, key, value, ipw, ipb, qb, kb, vb);
    flash_kernel <<<dim3(T_LEN / 64, BH),             256, 0, stream>>>(
        qb, kb, vb, ho, mws, lws);
    avg_kernel   <<<dim3(T_LEN / 64, T_LEN / 64, BATCH), 256, 0, stream>>>(
        qb, kb, mws, lws, attn_avg);
    outproj_kernel<<<dim3(MROWS / 64, EMB / 64),      256, 0, stream>>>(
        ho, opw, opb, out);
}

// Round 4
// 284.354 us; speedup vs baseline: 4.5859x; 1.3695x over previous
//
#include <hip/hip_runtime.h>
#include <math.h>

#define T_LEN 2048
#define BATCH 2
#define EMB 1024
#define NHEAD 16
#define HDIM 64
#define BH (BATCH*NHEAD)          // 32
#define MROWS (T_LEN*BATCH)       // 4096
#define SCALING 0.125f            // 1/sqrt(64)
#define HEADBUF ((size_t)BH*T_LEN*HDIM)   // 4,194,304 elements

typedef __attribute__((ext_vector_type(8))) short bf16x8;
typedef __attribute__((ext_vector_type(4))) float f32x4;

#define MFMA16(a,b,c) __builtin_amdgcn_mfma_f32_16x16x32_bf16(a,b,c,0,0,0)

__device__ __forceinline__ short f2bf(float f) {
    union { float f; unsigned u; } v; v.f = f;
    unsigned r = (v.u + 0x7FFFu + ((v.u >> 16) & 1u)) >> 16;   // RNE
    return (short)(unsigned short)r;
}
__device__ __forceinline__ float bf2f(short s) {
    union { unsigned u; float f; } v; v.u = ((unsigned)(unsigned short)s) << 16;
    return v.f;
}

// ---------------------------------------------------------------------------
// Kernel 1: fused QKV in-projection, bf16 MFMA. 128x128 tile, BK=64.
// nBase spans [0,3072): which = nBase>>10 selects X and dst. W row = nBase+r
// (NOT which*EMB + nBase + r -- that was the R3 bug).
// grid: (MROWS/128=32, 3*EMB/128=24), block 256
// ---------------------------------------------------------------------------
__global__ __launch_bounds__(256) void inproj_gemm(
    const float* __restrict__ Xq, const float* __restrict__ Xk,
    const float* __restrict__ Xv, const float* __restrict__ W,
    const float* __restrict__ bias,
    short* __restrict__ qb, short* __restrict__ kbuf, short* __restrict__ vbuf)
{
    const int mBase = blockIdx.x * 128;
    const int nBase = blockIdx.y * 128;
    const int which = nBase >> 10;
    const float* __restrict__ X = (which == 0) ? Xq : (which == 1) ? Xk : Xv;
    short* __restrict__ dst = (which == 0) ? qb : (which == 1) ? kbuf : vbuf;

    __shared__ short Ast[128][72];
    __shared__ short Bst[128][72];

    const int tid  = threadIdx.x;
    const int lane = tid & 63;
    const int w    = tid >> 6;
    const int wr   = w >> 1, wc = w & 1;
    const int lr   = lane & 15, lg = lane >> 4;

    f32x4 acc[4][4] = {};

    for (int kb = 0; kb < EMB; kb += 64) {
        __syncthreads();
        #pragma unroll
        for (int it = 0; it < 4; ++it) {
            int c = tid + 256 * it;          // 0..1023
            int r = c >> 3, kc = c & 7;
            const float* sa = &X[(size_t)(mBase + r) * EMB + kb + kc * 8];
            float4 f0 = *(const float4*)sa;
            float4 f1 = *(const float4*)(sa + 4);
            bf16x8 av;
            av[0]=f2bf(f0.x); av[1]=f2bf(f0.y); av[2]=f2bf(f0.z); av[3]=f2bf(f0.w);
            av[4]=f2bf(f1.x); av[5]=f2bf(f1.y); av[6]=f2bf(f1.z); av[7]=f2bf(f1.w);
            *(bf16x8*)&Ast[r][kc * 8] = av;
            const float* sb = &W[(size_t)(nBase + r) * EMB + kb + kc * 8];
            float4 g0 = *(const float4*)sb;
            float4 g1 = *(const float4*)(sb + 4);
            bf16x8 bv;
            bv[0]=f2bf(g0.x); bv[1]=f2bf(g0.y); bv[2]=f2bf(g0.z); bv[3]=f2bf(g0.w);
            bv[4]=f2bf(g1.x); bv[5]=f2bf(g1.y); bv[6]=f2bf(g1.z); bv[7]=f2bf(g1.w);
            *(bf16x8*)&Bst[r][kc * 8] = bv;
        }
        __syncthreads();
        #pragma unroll
        for (int ks = 0; ks < 2; ++ks) {
            bf16x8 af[4], bfr[4];
            #pragma unroll
            for (int rg = 0; rg < 4; ++rg)
                af[rg] = *(const bf16x8*)&Ast[wr * 64 + rg * 16 + lr][ks * 32 + lg * 8];
            #pragma unroll
            for (int cg = 0; cg < 4; ++cg)
                bfr[cg] = *(const bf16x8*)&Bst[wc * 64 + cg * 16 + lr][ks * 32 + lg * 8];
            #pragma unroll
            for (int rg = 0; rg < 4; ++rg)
                #pragma unroll
                for (int cg = 0; cg < 4; ++cg)
                    acc[rg][cg] = MFMA16(af[rg], bfr[cg], acc[rg][cg]);
        }
    }

    #pragma unroll
    for (int rg = 0; rg < 4; ++rg) {
        #pragma unroll
        for (int cg = 0; cg < 4; ++cg) {
            int n  = nBase + wc * 64 + cg * 16 + lr;
            int e  = n & 1023;
            int h  = e >> 6, dd = e & 63;
            float bs = bias[n];
            #pragma unroll
            for (int ri = 0; ri < 4; ++ri) {
                int m = mBase + wr * 64 + rg * 16 + lg * 4 + ri;
                int t = m >> 1, b = m & 1;
                float val = acc[rg][cg][ri] + bs;
                if (which == 0) val *= SCALING;
                dst[((size_t)(b * NHEAD + h) * T_LEN + t) * HDIM + dd] = f2bf(val);
            }
        }
    }
}

// ---------------------------------------------------------------------------
// Kernel 2: flash attention, swapped-QK^T bf16 MFMA.
// Lane holds S[s(16 vals)][q=lane&15]; softmax = in-lane + 2 shfl_xor.
// V^T in XOR-swizzled LDS (conflict-free write+read).
// grid: (T_LEN/64=32, BH=32), block 256
// ---------------------------------------------------------------------------
__global__ __launch_bounds__(256) void flash_kernel(
    const short* __restrict__ qb, const short* __restrict__ kbuf,
    const short* __restrict__ vbuf, float* __restrict__ ho,
    float* __restrict__ mws, float* __restrict__ lws)
{
    const int qt = blockIdx.x;
    const int hb = blockIdx.y;

    __shared__ short Kst[64][72];   // [s][d], pad-72: conflict-free
    __shared__ short VT [64][64];   // [d][s], XOR-swizzled bytes
    __shared__ short Pst[64][72];   // [q][s], wave-private 16-row slices

    const int tid  = threadIdx.x;
    const int lane = tid & 63;
    const int w    = tid >> 6;
    const int lr   = lane & 15, lg = lane >> 4;

    // Q fragments: B-operand, q-row = lr
    bf16x8 qa0, qa1;
    {
        const short* qsrc = qb + ((size_t)hb * T_LEN + qt * 64 + w * 16 + lr) * HDIM;
        qa0 = *(const bf16x8*)(qsrc + lg * 8);
        qa1 = *(const bf16x8*)(qsrc + 32 + lg * 8);
    }

    float m_r = -INFINITY, l_r = 0.f;     // for q = lr (replicated over lg)
    f32x4 o_acc[4] = {};                  // [dsub]; reg ri -> q = lg*4+ri

    for (int st = 0; st < T_LEN / 64; ++st) {
        __syncthreads();
        // stage K row-major
        #pragma unroll
        for (int it = 0; it < 2; ++it) {
            int c = tid + 256 * it;
            int r = c >> 3, kc = c & 7;
            *(bf16x8*)&Kst[r][kc * 8] =
                *(const bf16x8*)(kbuf + ((size_t)hb * T_LEN + st * 64 + r) * HDIM + kc * 8);
        }
        // stage V transposed into swizzled VT
        {
            int dc = tid & 7, s0 = (tid >> 3) * 2;
            const short* v0 = vbuf + ((size_t)hb * T_LEN + st * 64 + s0) * HDIM + dc * 8;
            bf16x8 va  = *(const bf16x8*)v0;
            bf16x8 vb2 = *(const bf16x8*)(v0 + HDIM);
            #pragma unroll
            for (int j = 0; j < 8; ++j) {
                int d = dc * 8 + j;
                unsigned pk = ((unsigned)(unsigned short)va[j]) |
                              (((unsigned)(unsigned short)vb2[j]) << 16);
                int byte = (d << 7) + (s0 << 1);
                byte ^= (((d & 7) ^ (d >> 3)) << 4);
                *(unsigned*)((char*)VT + byte) = pk;
            }
        }
        __syncthreads();

        // QK^T swapped: sc[sg] holds S[s = sg*16 + lg*4+ri][q = lr]
        f32x4 sc[4] = {};
        #pragma unroll
        for (int sg = 0; sg < 4; ++sg) {
            bf16x8 kf0 = *(const bf16x8*)&Kst[sg * 16 + lr][lg * 8];
            bf16x8 kf1 = *(const bf16x8*)&Kst[sg * 16 + lr][32 + lg * 8];
            sc[sg] = MFMA16(kf0, qa0, sc[sg]);
            sc[sg] = MFMA16(kf1, qa1, sc[sg]);
        }

        // online softmax for q = lr: in-lane over 16 + 2 shuffles
        float mx = sc[0][0];
        #pragma unroll
        for (int sg = 0; sg < 4; ++sg)
            #pragma unroll
            for (int ri = 0; ri < 4; ++ri)
                mx = fmaxf(mx, sc[sg][ri]);
        mx = fmaxf(mx, __shfl_xor(mx, 16));
        mx = fmaxf(mx, __shfl_xor(mx, 32));
        float mnew = fmaxf(m_r, mx);
        float scl  = __expf(m_r - mnew);
        float p[4][4], psum = 0.f;
        #pragma unroll
        for (int sg = 0; sg < 4; ++sg)
            #pragma unroll
            for (int ri = 0; ri < 4; ++ri) {
                p[sg][ri] = __expf(sc[sg][ri] - mnew);
                psum += p[sg][ri];
            }
        psum += __shfl_xor(psum, 16);
        psum += __shfl_xor(psum, 32);
        l_r = l_r * scl + psum;
        m_r = mnew;

        // redistribute scl to o_acc's q = lg*4+ri
        float sclq[4];
        #pragma unroll
        for (int ri = 0; ri < 4; ++ri) sclq[ri] = __shfl(scl, lg * 20 + ri);
        #pragma unroll
        for (int dsub = 0; dsub < 4; ++dsub)
            #pragma unroll
            for (int ri = 0; ri < 4; ++ri)
                o_acc[dsub][ri] *= sclq[ri];

        // P -> bf16 -> LDS: lane writes 4 x b64 (row q=lr, s-quads)
        #pragma unroll
        for (int sg = 0; sg < 4; ++sg) {
            unsigned lo = ((unsigned)(unsigned short)f2bf(p[sg][0])) |
                          (((unsigned)(unsigned short)f2bf(p[sg][1])) << 16);
            unsigned hi = ((unsigned)(unsigned short)f2bf(p[sg][2])) |
                          (((unsigned)(unsigned short)f2bf(p[sg][3])) << 16);
            uint2 pk; pk.x = lo; pk.y = hi;
            *(uint2*)&Pst[w * 16 + lr][sg * 16 + lg * 4] = pk;
        }

        // PV: O[q][d] += P[q][s] * V[s][d]
        #pragma unroll
        for (int ks = 0; ks < 2; ++ks) {
            bf16x8 pa = *(const bf16x8*)&Pst[w * 16 + lr][ks * 32 + lg * 8];
            #pragma unroll
            for (int dsub = 0; dsub < 4; ++dsub) {
                int d = dsub * 16 + lr;
                int byte = (d << 7) + ((ks * 32 + lg * 8) << 1);
                byte ^= (((d & 7) ^ (d >> 3)) << 4);
                bf16x8 vf = *(const bf16x8*)((char*)VT + byte);
                o_acc[dsub] = MFMA16(pa, vf, o_acc[dsub]);
            }
        }
    }

    // epilogue
    float inv = 1.0f / l_r;
    float invq[4];
    #pragma unroll
    for (int ri = 0; ri < 4; ++ri) invq[ri] = __shfl(inv, lg * 20 + ri);
    #pragma unroll
    for (int ri = 0; ri < 4; ++ri) {
        int row = qt * 64 + w * 16 + lg * 4 + ri;
        #pragma unroll
        for (int dsub = 0; dsub < 4; ++dsub)
            ho[((size_t)hb * T_LEN + row) * HDIM + dsub * 16 + lr] = o_acc[dsub][ri] * invq[ri];
    }
    if (lg == 0) {
        int row = qt * 64 + w * 16 + lr;
        mws[(size_t)hb * T_LEN + row] = m_r;
        lws[(size_t)hb * T_LEN + row] = l_r;
    }
}

// ---------------------------------------------------------------------------
// Kernel 3: attn_avg via MFMA score recompute, probs from stored m/l.
// grid: (32 st, 32 qt, 2 b), block 256
// ---------------------------------------------------------------------------
__global__ __launch_bounds__(256) void avg_kernel(
    const short* __restrict__ qb, const short* __restrict__ kbuf,
    const float* __restrict__ mws, const float* __restrict__ lws,
    float* __restrict__ attn_avg)
{
    const int st = blockIdx.x;
    const int qt = blockIdx.y;
    const int b  = blockIdx.z;

    __shared__ short Kst[64][72];

    const int tid  = threadIdx.x;
    const int lane = tid & 63;
    const int w    = tid >> 6;
    const int lr   = lane & 15, lg = lane >> 4;

    f32x4 acc[4] = {};

    for (int h = 0; h < NHEAD; ++h) {
        const int hb = b * NHEAD + h;
        __syncthreads();
        #pragma unroll
        for (int it = 0; it < 2; ++it) {
            int c = tid + 256 * it;
            int r = c >> 3, kc = c & 7;
            *(bf16x8*)&Kst[r][kc * 8] =
                *(const bf16x8*)(kbuf + ((size_t)hb * T_LEN + st * 64 + r) * HDIM + kc * 8);
        }
        __syncthreads();

        const short* qsrc = qb + ((size_t)hb * T_LEN + qt * 64 + w * 16 + lr) * HDIM;
        bf16x8 qa0 = *(const bf16x8*)(qsrc + lg * 8);
        bf16x8 qa1 = *(const bf16x8*)(qsrc + 32 + lg * 8);

        f32x4 sc[4] = {};
        #pragma unroll
        for (int sg = 0; sg < 4; ++sg) {
            bf16x8 kf0 = *(const bf16x8*)&Kst[sg * 16 + lr][lg * 8];
            bf16x8 kf1 = *(const bf16x8*)&Kst[sg * 16 + lr][32 + lg * 8];
            sc[sg] = MFMA16(qa0, kf0, sc[sg]);
            sc[sg] = MFMA16(qa1, kf1, sc[sg]);
        }

        #pragma unroll
        for (int ri = 0; ri < 4; ++ri) {
            int row = qt * 64 + w * 16 + lg * 4 + ri;
            float mm  = mws[(size_t)hb * T_LEN + row];
            float inv = 1.0f / lws[(size_t)hb * T_LEN + row];
            #pragma unroll
            for (int sg = 0; sg < 4; ++sg)
                acc[sg][ri] += __expf(sc[sg][ri] - mm) * inv;
        }
    }

    const float invH = 1.0f / (float)NHEAD;
    #pragma unroll
    for (int ri = 0; ri < 4; ++ri) {
        int row = qt * 64 + w * 16 + lg * 4 + ri;
        #pragma unroll
        for (int sg = 0; sg < 4; ++sg)
            attn_avg[((size_t)b * T_LEN + row) * T_LEN + st * 64 + sg * 16 + lr] =
                acc[sg][ri] * invH;
    }
}

// ---------------------------------------------------------------------------
// Kernel 4: out-projection, bf16 MFMA with split-ho compensation:
// ho = h1 + h2 (both bf16), out = h1*W + h2*W (fp32 accum).
// grid: (MROWS/128=32, EMB/128=8), block 256
// ---------------------------------------------------------------------------
__global__ __launch_bounds__(256) void outproj_gemm(
    const float* __restrict__ ho, const float* __restrict__ Wo,
    const float* __restrict__ bo, float* __restrict__ out)
{
    const int mBase = blockIdx.x * 128;
    const int nBase = blockIdx.y * 128;

    __shared__ short A1st[128][72];
    __shared__ short A2st[128][72];
    __shared__ short Bst [128][72];

    const int tid  = threadIdx.x;
    const int lane = tid & 63;
    const int w    = tid >> 6;
    const int wr   = w >> 1, wc = w & 1;
    const int lr   = lane & 15, lg = lane >> 4;

    f32x4 acc[4][4] = {};

    for (int kb = 0; kb < EMB; kb += 64) {
        const int h = kb >> 6;
        __syncthreads();
        #pragma unroll
        for (int it = 0; it < 4; ++it) {
            int c = tid + 256 * it;
            int r = c >> 3, kc = c & 7;
            int m = mBase + r;
            int t = m >> 1, b = m & 1;
            const float* sa = &ho[((size_t)(b * NHEAD + h) * T_LEN + t) * HDIM + kc * 8];
            float4 f0 = *(const float4*)sa;
            float4 f1 = *(const float4*)(sa + 4);
            float fv[8] = {f0.x, f0.y, f0.z, f0.w, f1.x, f1.y, f1.z, f1.w};
            bf16x8 a1, a2;
            #pragma unroll
            for (int j = 0; j < 8; ++j) {
                short hi = f2bf(fv[j]);
                a1[j] = hi;
                a2[j] = f2bf(fv[j] - bf2f(hi));
            }
            *(bf16x8*)&A1st[r][kc * 8] = a1;
            *(bf16x8*)&A2st[r][kc * 8] = a2;
            const float* sb = &Wo[(size_t)(nBase + r) * EMB + kb + kc * 8];
            float4 g0 = *(const float4*)sb;
            float4 g1 = *(const float4*)(sb + 4);
            bf16x8 bv;
            bv[0]=f2bf(g0.x); bv[1]=f2bf(g0.y); bv[2]=f2bf(g0.z); bv[3]=f2bf(g0.w);
            bv[4]=f2bf(g1.x); bv[5]=f2bf(g1.y); bv[6]=f2bf(g1.z); bv[7]=f2bf(g1.w);
            *(bf16x8*)&Bst[r][kc * 8] = bv;
        }
        __syncthreads();
        #pragma unroll
        for (int ks = 0; ks < 2; ++ks) {
            bf16x8 a1[4], a2[4], bfr[4];
            #pragma unroll
            for (int rg = 0; rg < 4; ++rg) {
                a1[rg] = *(const bf16x8*)&A1st[wr * 64 + rg * 16 + lr][ks * 32 + lg * 8];
                a2[rg] = *(const bf16x8*)&A2st[wr * 64 + rg * 16 + lr][ks * 32 + lg * 8];
            }
            #pragma unroll
            for (int cg = 0; cg < 4; ++cg)
                bfr[cg] = *(const bf16x8*)&Bst[wc * 64 + cg * 16 + lr][ks * 32 + lg * 8];
            #pragma unroll
            for (int rg = 0; rg < 4; ++rg)
                #pragma unroll
                for (int cg = 0; cg < 4; ++cg) {
                    acc[rg][cg] = MFMA16(a1[rg], bfr[cg], acc[rg][cg]);
                    acc[rg][cg] = MFMA16(a2[rg], bfr[cg], acc[rg][cg]);
                }
        }
    }

    #pragma unroll
    for (int rg = 0; rg < 4; ++rg) {
        #pragma unroll
        for (int cg = 0; cg < 4; ++cg) {
            int n = nBase + wc * 64 + cg * 16 + lr;
            float bs = bo[n];
            #pragma unroll
            for (int ri = 0; ri < 4; ++ri) {
                int m = mBase + wr * 64 + rg * 16 + lg * 4 + ri;
                out[(size_t)m * EMB + n] = acc[rg][cg][ri] + bs;
            }
        }
    }
}

// ---------------------------------------------------------------------------
extern "C" void kernel_launch(void* const* d_in, const int* in_sizes, int n_in,
                              void* d_out, int out_size, void* d_ws, size_t ws_size,
                              hipStream_t stream)
{
    const float* query = (const float*)d_in[0];
    const float* key   = (const float*)d_in[1];
    const float* value = (const float*)d_in[2];
    const float* ipw   = (const float*)d_in[3];
    const float* ipb   = (const float*)d_in[4];
    const float* opw   = (const float*)d_in[5];
    const float* opb   = (const float*)d_in[6];

    short* qb  = (short*)d_ws;                 // bf16, HEADBUF each
    short* kb  = qb + HEADBUF;
    short* vb  = kb + HEADBUF;
    float* ho  = (float*)(vb + HEADBUF);       // fp32, HEADBUF
    float* mws = ho + HEADBUF;                 // BH*T_LEN
    float* lws = mws + (size_t)BH * T_LEN;

    float* out      = (float*)d_out;
    float* attn_avg = out + (size_t)MROWS * EMB;

    inproj_gemm  <<<dim3(MROWS / 128, 3 * EMB / 128), 256, 0, stream>>>(
        query, key, value, ipw, ipb, qb, kb, vb);
    flash_kernel <<<dim3(T_LEN / 64, BH),             256, 0, stream>>>(
        qb, kb, vb, ho, mws, lws);
    avg_kernel   <<<dim3(T_LEN / 64, T_LEN / 64, BATCH), 256, 0, stream>>>(
        qb, kb, mws, lws, attn_avg);
    outproj_gemm <<<dim3(MROWS / 128, EMB / 128),     256, 0, stream>>>(
        ho, opw, opb, out);
}

// Round 5
// 253.178 us; speedup vs baseline: 5.1506x; 1.1231x over previous
//
#include <hip/hip_runtime.h>
#include <math.h>

#define T_LEN 2048
#define BATCH 2
#define EMB 1024
#define NHEAD 16
#define HDIM 64
#define BH (BATCH*NHEAD)          // 32
#define MROWS (T_LEN*BATCH)       // 4096
#define SCALING 0.125f            // 1/sqrt(64)
#define HEADBUF ((size_t)BH*T_LEN*HDIM)   // 4,194,304 elements

typedef __attribute__((ext_vector_type(8))) short bf16x8;
typedef __attribute__((ext_vector_type(4))) float f32x4;

#define MFMA16(a,b,c) __builtin_amdgcn_mfma_f32_16x16x32_bf16(a,b,c,0,0,0)

__device__ __forceinline__ short f2bf(float f) {
    union { float f; unsigned u; } v; v.f = f;
    unsigned r = (v.u + 0x7FFFu + ((v.u >> 16) & 1u)) >> 16;   // RNE
    return (short)(unsigned short)r;
}
__device__ __forceinline__ float bf2f(short s) {
    union { unsigned u; float f; } v; v.u = ((unsigned)(unsigned short)s) << 16;
    return v.f;
}
// async global->LDS, 16B per lane; lds dest = wave-uniform base + lane*16
__device__ __forceinline__ void gload16(const void* g, void* l) {
    __builtin_amdgcn_global_load_lds(
        (const __attribute__((address_space(1))) unsigned*)g,
        (__attribute__((address_space(3))) unsigned*)l, 16, 0, 0);
}

// ---------------------------------------------------------------------------
// Kernel 0: one-shot fp32 -> bf16 of [Xq | Xk | Xv | W | Wo] into contiguous
// ws region (16,777,216 elements exactly). grid 8192 x 256, 8 elem/thread.
// ---------------------------------------------------------------------------
__global__ __launch_bounds__(256) void tobf16_kernel(
    const float* __restrict__ q, const float* __restrict__ k,
    const float* __restrict__ v, const float* __restrict__ w,
    const float* __restrict__ wo, short* __restrict__ out)
{
    size_t i8 = ((size_t)blockIdx.x * 256 + threadIdx.x) * 8;
    const float* src; size_t off;
    if (i8 < 12582912) {            // 3 x 4,194,304
        int sel = (int)(i8 >> 22);
        src = (sel == 0) ? q : (sel == 1) ? k : v;
        off = i8 & 4194303;
    } else if (i8 < 15728640) {     // + 3,145,728
        src = w;  off = i8 - 12582912;
    } else {                        // + 1,048,576
        src = wo; off = i8 - 15728640;
    }
    float4 f0 = *(const float4*)(src + off);
    float4 f1 = *(const float4*)(src + off + 4);
    bf16x8 o;
    o[0]=f2bf(f0.x); o[1]=f2bf(f0.y); o[2]=f2bf(f0.z); o[3]=f2bf(f0.w);
    o[4]=f2bf(f1.x); o[5]=f2bf(f1.y); o[6]=f2bf(f1.z); o[7]=f2bf(f1.w);
    *(bf16x8*)(out + i8) = o;
}

// ---------------------------------------------------------------------------
// Kernel 1: fused QKV in-projection, pure bf16, global_load_lds staging.
// 128x128 tile, BK=64, linear LDS [128][64] (m97 structure).
// grid: (32, 24), block 256
// ---------------------------------------------------------------------------
__global__ __launch_bounds__(256) void inproj_gemm(
    const short* __restrict__ Xq, const short* __restrict__ Xk,
    const short* __restrict__ Xv, const short* __restrict__ Wb,
    const float* __restrict__ bias,
    short* __restrict__ qbuf, short* __restrict__ kbuf, short* __restrict__ vbuf)
{
    const int mBase = blockIdx.x * 128;
    const int nBase = blockIdx.y * 128;
    const int which = nBase >> 10;
    const short* __restrict__ X = (which == 0) ? Xq : (which == 1) ? Xk : Xv;
    short* __restrict__ dst = (which == 0) ? qbuf : (which == 1) ? kbuf : vbuf;

    __shared__ short Ast[128][64];
    __shared__ short Bst[128][64];

    const int tid  = threadIdx.x;
    const int lane = tid & 63;
    const int w    = tid >> 6;
    const int wr   = w >> 1, wc = w & 1;
    const int lr   = lane & 15, lg = lane >> 4;
    const int srow = tid >> 3;          // 0..31
    const int scol = (tid & 7) * 8;

    f32x4 acc[4][4] = {};

    for (int kb = 0; kb < EMB; kb += 64) {
        __syncthreads();
        #pragma unroll
        for (int j = 0; j < 4; ++j) {
            gload16(X  + (size_t)(mBase + j * 32 + srow) * EMB + kb + scol,
                    (char*)Ast + j * 4096 + w * 1024);
            gload16(Wb + (size_t)(nBase + j * 32 + srow) * EMB + kb + scol,
                    (char*)Bst + j * 4096 + w * 1024);
        }
        __syncthreads();
        #pragma unroll
        for (int ks = 0; ks < 2; ++ks) {
            bf16x8 af[4], bfr[4];
            #pragma unroll
            for (int rg = 0; rg < 4; ++rg)
                af[rg] = *(const bf16x8*)&Ast[wr * 64 + rg * 16 + lr][ks * 32 + lg * 8];
            #pragma unroll
            for (int cg = 0; cg < 4; ++cg)
                bfr[cg] = *(const bf16x8*)&Bst[wc * 64 + cg * 16 + lr][ks * 32 + lg * 8];
            #pragma unroll
            for (int rg = 0; rg < 4; ++rg)
                #pragma unroll
                for (int cg = 0; cg < 4; ++cg)
                    acc[rg][cg] = MFMA16(af[rg], bfr[cg], acc[rg][cg]);
        }
    }

    #pragma unroll
    for (int rg = 0; rg < 4; ++rg) {
        #pragma unroll
        for (int cg = 0; cg < 4; ++cg) {
            int n  = nBase + wc * 64 + cg * 16 + lr;
            int e  = n & 1023;
            int h  = e >> 6, dd = e & 63;
            float bs = bias[n];
            #pragma unroll
            for (int ri = 0; ri < 4; ++ri) {
                int m = mBase + wr * 64 + rg * 16 + lg * 4 + ri;
                int t = m >> 1, b = m & 1;
                float val = acc[rg][cg][ri] + bs;
                if (which == 0) val *= SCALING;
                dst[((size_t)(b * NHEAD + h) * T_LEN + t) * HDIM + dd] = f2bf(val);
            }
        }
    }
}

// ---------------------------------------------------------------------------
// Kernel 2: flash attention, swapped-QK^T bf16 MFMA (unchanged compute).
// Epilogue writes split-bf16 h1/h2 (h1+h2 ~= o) for the bf16 out-projection.
// grid: (32, 32), block 256
// ---------------------------------------------------------------------------
__global__ __launch_bounds__(256) void flash_kernel(
    const short* __restrict__ qb, const short* __restrict__ kbuf,
    const short* __restrict__ vbuf, short* __restrict__ h1,
    short* __restrict__ h2, float* __restrict__ mws, float* __restrict__ lws)
{
    const int qt = blockIdx.x;
    const int hb = blockIdx.y;

    __shared__ short Kst[64][72];   // [s][d], pad-72: conflict-free reads
    __shared__ short VT [64][64];   // [d][s], XOR-swizzled bytes
    __shared__ short Pst[64][72];   // [q][s], wave-private 16-row slices

    const int tid  = threadIdx.x;
    const int lane = tid & 63;
    const int w    = tid >> 6;
    const int lr   = lane & 15, lg = lane >> 4;

    bf16x8 qa0, qa1;
    {
        const short* qsrc = qb + ((size_t)hb * T_LEN + qt * 64 + w * 16 + lr) * HDIM;
        qa0 = *(const bf16x8*)(qsrc + lg * 8);
        qa1 = *(const bf16x8*)(qsrc + 32 + lg * 8);
    }

    float m_r = -INFINITY, l_r = 0.f;     // for q = lr (replicated over lg)
    f32x4 o_acc[4] = {};                  // [dsub]; reg ri -> q = lg*4+ri

    for (int st = 0; st < T_LEN / 64; ++st) {
        __syncthreads();
        #pragma unroll
        for (int it = 0; it < 2; ++it) {
            int c = tid + 256 * it;
            int r = c >> 3, kc = c & 7;
            *(bf16x8*)&Kst[r][kc * 8] =
                *(const bf16x8*)(kbuf + ((size_t)hb * T_LEN + st * 64 + r) * HDIM + kc * 8);
        }
        {
            int dc = tid & 7, s0 = (tid >> 3) * 2;
            const short* v0 = vbuf + ((size_t)hb * T_LEN + st * 64 + s0) * HDIM + dc * 8;
            bf16x8 va  = *(const bf16x8*)v0;
            bf16x8 vb2 = *(const bf16x8*)(v0 + HDIM);
            #pragma unroll
            for (int j = 0; j < 8; ++j) {
                int d = dc * 8 + j;
                unsigned pk = ((unsigned)(unsigned short)va[j]) |
                              (((unsigned)(unsigned short)vb2[j]) << 16);
                int byte = (d << 7) + (s0 << 1);
                byte ^= (((d & 7) ^ (d >> 3)) << 4);
                *(unsigned*)((char*)VT + byte) = pk;
            }
        }
        __syncthreads();

        f32x4 sc[4] = {};
        #pragma unroll
        for (int sg = 0; sg < 4; ++sg) {
            bf16x8 kf0 = *(const bf16x8*)&Kst[sg * 16 + lr][lg * 8];
            bf16x8 kf1 = *(const bf16x8*)&Kst[sg * 16 + lr][32 + lg * 8];
            sc[sg] = MFMA16(kf0, qa0, sc[sg]);
            sc[sg] = MFMA16(kf1, qa1, sc[sg]);
        }

        float mx = sc[0][0];
        #pragma unroll
        for (int sg = 0; sg < 4; ++sg)
            #pragma unroll
            for (int ri = 0; ri < 4; ++ri)
                mx = fmaxf(mx, sc[sg][ri]);
        mx = fmaxf(mx, __shfl_xor(mx, 16));
        mx = fmaxf(mx, __shfl_xor(mx, 32));
        float mnew = fmaxf(m_r, mx);
        float scl  = __expf(m_r - mnew);
        float p[4][4], psum = 0.f;
        #pragma unroll
        for (int sg = 0; sg < 4; ++sg)
            #pragma unroll
            for (int ri = 0; ri < 4; ++ri) {
                p[sg][ri] = __expf(sc[sg][ri] - mnew);
                psum += p[sg][ri];
            }
        psum += __shfl_xor(psum, 16);
        psum += __shfl_xor(psum, 32);
        l_r = l_r * scl + psum;
        m_r = mnew;

        float sclq[4];
        #pragma unroll
        for (int ri = 0; ri < 4; ++ri) sclq[ri] = __shfl(scl, lg * 20 + ri);
        #pragma unroll
        for (int dsub = 0; dsub < 4; ++dsub)
            #pragma unroll
            for (int ri = 0; ri < 4; ++ri)
                o_acc[dsub][ri] *= sclq[ri];

        #pragma unroll
        for (int sg = 0; sg < 4; ++sg) {
            unsigned lo = ((unsigned)(unsigned short)f2bf(p[sg][0])) |
                          (((unsigned)(unsigned short)f2bf(p[sg][1])) << 16);
            unsigned hi = ((unsigned)(unsigned short)f2bf(p[sg][2])) |
                          (((unsigned)(unsigned short)f2bf(p[sg][3])) << 16);
            uint2 pk; pk.x = lo; pk.y = hi;
            *(uint2*)&Pst[w * 16 + lr][sg * 16 + lg * 4] = pk;
        }

        #pragma unroll
        for (int ks = 0; ks < 2; ++ks) {
            bf16x8 pa = *(const bf16x8*)&Pst[w * 16 + lr][ks * 32 + lg * 8];
            #pragma unroll
            for (int dsub = 0; dsub < 4; ++dsub) {
                int d = dsub * 16 + lr;
                int byte = (d << 7) + ((ks * 32 + lg * 8) << 1);
                byte ^= (((d & 7) ^ (d >> 3)) << 4);
                bf16x8 vf = *(const bf16x8*)((char*)VT + byte);
                o_acc[dsub] = MFMA16(pa, vf, o_acc[dsub]);
            }
        }
    }

    float inv = 1.0f / l_r;
    float invq[4];
    #pragma unroll
    for (int ri = 0; ri < 4; ++ri) invq[ri] = __shfl(inv, lg * 20 + ri);
    #pragma unroll
    for (int ri = 0; ri < 4; ++ri) {
        int row = qt * 64 + w * 16 + lg * 4 + ri;
        #pragma unroll
        for (int dsub = 0; dsub < 4; ++dsub) {
            float x = o_acc[dsub][ri] * invq[ri];
            size_t idx = ((size_t)hb * T_LEN + row) * HDIM + dsub * 16 + lr;
            short a = f2bf(x);
            h1[idx] = a;
            h2[idx] = f2bf(x - bf2f(a));
        }
    }
    if (lg == 0) {
        int row = qt * 64 + w * 16 + lr;
        mws[(size_t)hb * T_LEN + row] = m_r;
        lws[(size_t)hb * T_LEN + row] = l_r;
    }
}

// ---------------------------------------------------------------------------
// Kernel 3: attn_avg. 4 heads staged per barrier-pair via global_load_lds
// (8 barriers/block instead of 32). Probs from stored m/l.
// grid: (32 st, 32 qt, 2 b), block 256
// ---------------------------------------------------------------------------
__global__ __launch_bounds__(256) void avg_kernel(
    const short* __restrict__ qbuf, const short* __restrict__ kbuf,
    const float* __restrict__ mws, const float* __restrict__ lws,
    float* __restrict__ attn_avg)
{
    const int st = blockIdx.x;
    const int qt = blockIdx.y;
    const int b  = blockIdx.z;

    __shared__ short K4[4][64][64];   // 32 KB, linear for gload_lds

    const int tid  = threadIdx.x;
    const int lane = tid & 63;
    const int w    = tid >> 6;
    const int lr   = lane & 15, lg = lane >> 4;

    f32x4 acc[4] = {};

    for (int rnd = 0; rnd < 4; ++rnd) {
        __syncthreads();
        #pragma unroll
        for (int hh = 0; hh < 4; ++hh) {
            int hb = b * NHEAD + rnd * 4 + hh;
            #pragma unroll
            for (int j = 0; j < 2; ++j) {
                int row = j * 32 + (tid >> 3);
                int col = (tid & 7) * 8;
                gload16(kbuf + ((size_t)hb * T_LEN + st * 64 + row) * HDIM + col,
                        (char*)K4[hh] + j * 4096 + w * 1024);
            }
        }
        __syncthreads();
        #pragma unroll
        for (int hh = 0; hh < 4; ++hh) {
            int hb = b * NHEAD + rnd * 4 + hh;
            const short* qsrc = qbuf + ((size_t)hb * T_LEN + qt * 64 + w * 16 + lr) * HDIM;
            bf16x8 qa0 = *(const bf16x8*)(qsrc + lg * 8);
            bf16x8 qa1 = *(const bf16x8*)(qsrc + 32 + lg * 8);

            f32x4 sc[4] = {};
            #pragma unroll
            for (int sg = 0; sg < 4; ++sg) {
                bf16x8 kf0 = *(const bf16x8*)&K4[hh][sg * 16 + lr][lg * 8];
                bf16x8 kf1 = *(const bf16x8*)&K4[hh][sg * 16 + lr][32 + lg * 8];
                sc[sg] = MFMA16(qa0, kf0, sc[sg]);
                sc[sg] = MFMA16(qa1, kf1, sc[sg]);
            }

            #pragma unroll
            for (int ri = 0; ri < 4; ++ri) {
                int row = qt * 64 + w * 16 + lg * 4 + ri;
                float mm  = mws[(size_t)hb * T_LEN + row];
                float inv = 1.0f / lws[(size_t)hb * T_LEN + row];
                #pragma unroll
                for (int sg = 0; sg < 4; ++sg)
                    acc[sg][ri] += __expf(sc[sg][ri] - mm) * inv;
            }
        }
    }

    const float invH = 1.0f / (float)NHEAD;
    #pragma unroll
    for (int ri = 0; ri < 4; ++ri) {
        int row = qt * 64 + w * 16 + lg * 4 + ri;
        #pragma unroll
        for (int sg = 0; sg < 4; ++sg)
            attn_avg[((size_t)b * T_LEN + row) * T_LEN + st * 64 + sg * 16 + lr] =
                acc[sg][ri] * invH;
    }
}

// ---------------------------------------------------------------------------
// Kernel 4: out-projection, bf16 MFMA, gload_lds staging of h1/h2/Wo(bf16).
// out = h1*Wo^T + h2*Wo^T + bo (fp32 accum).
// grid: (32, 8), block 256
// ---------------------------------------------------------------------------
__global__ __launch_bounds__(256) void outproj_gemm(
    const short* __restrict__ h1, const short* __restrict__ h2,
    const short* __restrict__ Wob, const float* __restrict__ bo,
    float* __restrict__ out)
{
    const int mBase = blockIdx.x * 128;
    const int nBase = blockIdx.y * 128;

    __shared__ short A1st[128][64];
    __shared__ short A2st[128][64];
    __shared__ short Bst [128][64];

    const int tid  = threadIdx.x;
    const int lane = tid & 63;
    const int w    = tid >> 6;
    const int wr   = w >> 1, wc = w & 1;
    const int lr   = lane & 15, lg = lane >> 4;
    const int srow = tid >> 3;
    const int scol = (tid & 7) * 8;

    f32x4 acc[4][4] = {};

    for (int kb = 0; kb < EMB; kb += 64) {
        const int h = kb >> 6;
        __syncthreads();
        #pragma unroll
        for (int j = 0; j < 4; ++j) {
            int m = mBase + j * 32 + srow;
            int t = m >> 1, b = m & 1;
            size_t aoff = ((size_t)(b * NHEAD + h) * T_LEN + t) * HDIM + scol;
            gload16(h1 + aoff, (char*)A1st + j * 4096 + w * 1024);
            gload16(h2 + aoff, (char*)A2st + j * 4096 + w * 1024);
            gload16(Wob + (size_t)(nBase + j * 32 + srow) * EMB + kb + scol,
                    (char*)Bst + j * 4096 + w * 1024);
        }
        __syncthreads();
        #pragma unroll
        for (int ks = 0; ks < 2; ++ks) {
            bf16x8 a1[4], a2[4], bfr[4];
            #pragma unroll
            for (int rg = 0; rg < 4; ++rg) {
                a1[rg] = *(const bf16x8*)&A1st[wr * 64 + rg * 16 + lr][ks * 32 + lg * 8];
                a2[rg] = *(const bf16x8*)&A2st[wr * 64 + rg * 16 + lr][ks * 32 + lg * 8];
            }
            #pragma unroll
            for (int cg = 0; cg < 4; ++cg)
                bfr[cg] = *(const bf16x8*)&Bst[wc * 64 + cg * 16 + lr][ks * 32 + lg * 8];
            #pragma unroll
            for (int rg = 0; rg < 4; ++rg)
                #pragma unroll
                for (int cg = 0; cg < 4; ++cg) {
                    acc[rg][cg] = MFMA16(a1[rg], bfr[cg], acc[rg][cg]);
                    acc[rg][cg] = MFMA16(a2[rg], bfr[cg], acc[rg][cg]);
                }
        }
    }

    #pragma unroll
    for (int rg = 0; rg < 4; ++rg) {
        #pragma unroll
        for (int cg = 0; cg < 4; ++cg) {
            int n = nBase + wc * 64 + cg * 16 + lr;
            float bs = bo[n];
            #pragma unroll
            for (int ri = 0; ri < 4; ++ri) {
                int m = mBase + wr * 64 + rg * 16 + lg * 4 + ri;
                out[(size_t)m * EMB + n] = acc[rg][cg][ri] + bs;
            }
        }
    }
}

// ---------------------------------------------------------------------------
extern "C" void kernel_launch(void* const* d_in, const int* in_sizes, int n_in,
                              void* d_out, int out_size, void* d_ws, size_t ws_size,
                              hipStream_t stream)
{
    const float* query = (const float*)d_in[0];
    const float* key   = (const float*)d_in[1];
    const float* value = (const float*)d_in[2];
    const float* ipw   = (const float*)d_in[3];
    const float* ipb   = (const float*)d_in[4];
    const float* opw   = (const float*)d_in[5];
    const float* opb   = (const float*)d_in[6];

    // ws layout (shorts). h1/h2/xvb double as Xq_bf/Xk_bf/Xv_bf during inproj
    // (dead before flash overwrites h1/h2). Total ~59.2 MB.
    short* qb  = (short*)d_ws;
    short* kb  = qb + HEADBUF;
    short* vb  = kb + HEADBUF;
    short* h1  = vb + HEADBUF;                     // inproj: Xq_bf
    short* h2  = h1 + HEADBUF;                     // inproj: Xk_bf
    short* xvb = h2 + HEADBUF;                     // inproj: Xv_bf
    short* wbf = xvb + HEADBUF;                    // 3*EMB*EMB
    short* wob = wbf + (size_t)3 * EMB * EMB;      // EMB*EMB
    float* mws = (float*)(wob + (size_t)EMB * EMB);
    float* lws = mws + (size_t)BH * T_LEN;

    float* out      = (float*)d_out;
    float* attn_avg = out + (size_t)MROWS * EMB;

    // [Xq|Xk|Xv|W|Wo] are contiguous starting at h1
    tobf16_kernel<<<8192, 256, 0, stream>>>(query, key, value, ipw, opw, h1);
    inproj_gemm  <<<dim3(MROWS / 128, 3 * EMB / 128), 256, 0, stream>>>(
        h1, h2, xvb, wbf, ipb, qb, kb, vb);
    flash_kernel <<<dim3(T_LEN / 64, BH),             256, 0, stream>>>(
        qb, kb, vb, h1, h2, mws, lws);
    avg_kernel   <<<dim3(T_LEN / 64, T_LEN / 64, BATCH), 256, 0, stream>>>(
        qb, kb, mws, lws, attn_avg);
    outproj_gemm <<<dim3(MROWS / 128, EMB / 128),     256, 0, stream>>>(
        h1, h2, wob, opb, out);
}

// Round 6
// 234.602 us; speedup vs baseline: 5.5584x; 1.0792x over previous
//
#include <hip/hip_runtime.h>
#include <math.h>

#define T_LEN 2048
#define BATCH 2
#define EMB 1024
#define NHEAD 16
#define HDIM 64
#define BH (BATCH*NHEAD)          // 32
#define MROWS (T_LEN*BATCH)       // 4096
// q scaling with log2(e) folded in: softmax runs in exp2 domain
#define QSCALE (0.125f * 1.4426950408889634f)
#define HEADBUF ((size_t)BH*T_LEN*HDIM)   // 4,194,304 elements

typedef __attribute__((ext_vector_type(8))) short bf16x8;
typedef __attribute__((ext_vector_type(4))) float f32x4;

#define MFMA16(a,b,c) __builtin_amdgcn_mfma_f32_16x16x32_bf16(a,b,c,0,0,0)

__device__ __forceinline__ short f2bf(float f) {
    union { float f; unsigned u; } v; v.f = f;
    unsigned r = (v.u + 0x7FFFu + ((v.u >> 16) & 1u)) >> 16;   // RNE
    return (short)(unsigned short)r;
}
__device__ __forceinline__ float bf2f(short s) {
    union { unsigned u; float f; } v; v.u = ((unsigned)(unsigned short)s) << 16;
    return v.f;
}
// pack two f32 -> 2xbf16 in one u32 (RNE), single HW instr
__device__ __forceinline__ unsigned cvtpk(float a, float b) {
    unsigned r;
    asm("v_cvt_pk_bf16_f32 %0, %1, %2" : "=v"(r) : "v"(a), "v"(b));
    return r;
}
// async global->LDS, 16B per lane; lds dest = wave-uniform base + lane*16
__device__ __forceinline__ void gload16(const void* g, void* l) {
    __builtin_amdgcn_global_load_lds(
        (const __attribute__((address_space(1))) unsigned*)g,
        (__attribute__((address_space(3))) unsigned*)l, 16, 0, 0);
}

// ---------------------------------------------------------------------------
// Kernel 0: one-shot fp32 -> bf16 of [Xq | Xk | Xv | W | Wo].
// ---------------------------------------------------------------------------
__global__ __launch_bounds__(256) void tobf16_kernel(
    const float* __restrict__ q, const float* __restrict__ k,
    const float* __restrict__ v, const float* __restrict__ w,
    const float* __restrict__ wo, short* __restrict__ out)
{
    size_t i8 = ((size_t)blockIdx.x * 256 + threadIdx.x) * 8;
    const float* src; size_t off;
    if (i8 < 12582912) {            // 3 x 4,194,304
        int sel = (int)(i8 >> 22);
        src = (sel == 0) ? q : (sel == 1) ? k : v;
        off = i8 & 4194303;
    } else if (i8 < 15728640) {     // + 3,145,728
        src = w;  off = i8 - 12582912;
    } else {                        // + 1,048,576
        src = wo; off = i8 - 15728640;
    }
    float4 f0 = *(const float4*)(src + off);
    float4 f1 = *(const float4*)(src + off + 4);
    bf16x8 o;
    o[0]=f2bf(f0.x); o[1]=f2bf(f0.y); o[2]=f2bf(f0.z); o[3]=f2bf(f0.w);
    o[4]=f2bf(f1.x); o[5]=f2bf(f1.y); o[6]=f2bf(f1.z); o[7]=f2bf(f1.w);
    *(bf16x8*)(out + i8) = o;
}

// ---------------------------------------------------------------------------
// Kernel 1: fused QKV in-projection, pure bf16, global_load_lds staging.
// grid: (32, 24), block 256.  q pre-scaled by QSCALE (exp2 domain).
// ---------------------------------------------------------------------------
__global__ __launch_bounds__(256) void inproj_gemm(
    const short* __restrict__ Xq, const short* __restrict__ Xk,
    const short* __restrict__ Xv, const short* __restrict__ Wb,
    const float* __restrict__ bias,
    short* __restrict__ qbuf, short* __restrict__ kbuf, short* __restrict__ vbuf)
{
    const int mBase = blockIdx.x * 128;
    const int nBase = blockIdx.y * 128;
    const int which = nBase >> 10;
    const short* __restrict__ X = (which == 0) ? Xq : (which == 1) ? Xk : Xv;
    short* __restrict__ dst = (which == 0) ? qbuf : (which == 1) ? kbuf : vbuf;

    __shared__ short Ast[128][64];
    __shared__ short Bst[128][64];

    const int tid  = threadIdx.x;
    const int lane = tid & 63;
    const int w    = tid >> 6;
    const int wr   = w >> 1, wc = w & 1;
    const int lr   = lane & 15, lg = lane >> 4;
    const int srow = tid >> 3;          // 0..31
    const int scol = (tid & 7) * 8;

    f32x4 acc[4][4] = {};

    for (int kb = 0; kb < EMB; kb += 64) {
        __syncthreads();
        #pragma unroll
        for (int j = 0; j < 4; ++j) {
            gload16(X  + (size_t)(mBase + j * 32 + srow) * EMB + kb + scol,
                    (char*)Ast + j * 4096 + w * 1024);
            gload16(Wb + (size_t)(nBase + j * 32 + srow) * EMB + kb + scol,
                    (char*)Bst + j * 4096 + w * 1024);
        }
        __syncthreads();
        #pragma unroll
        for (int ks = 0; ks < 2; ++ks) {
            bf16x8 af[4], bfr[4];
            #pragma unroll
            for (int rg = 0; rg < 4; ++rg)
                af[rg] = *(const bf16x8*)&Ast[wr * 64 + rg * 16 + lr][ks * 32 + lg * 8];
            #pragma unroll
            for (int cg = 0; cg < 4; ++cg)
                bfr[cg] = *(const bf16x8*)&Bst[wc * 64 + cg * 16 + lr][ks * 32 + lg * 8];
            #pragma unroll
            for (int rg = 0; rg < 4; ++rg)
                #pragma unroll
                for (int cg = 0; cg < 4; ++cg)
                    acc[rg][cg] = MFMA16(af[rg], bfr[cg], acc[rg][cg]);
        }
    }

    #pragma unroll
    for (int rg = 0; rg < 4; ++rg) {
        #pragma unroll
        for (int cg = 0; cg < 4; ++cg) {
            int n  = nBase + wc * 64 + cg * 16 + lr;
            int e  = n & 1023;
            int h  = e >> 6, dd = e & 63;
            float bs = bias[n];
            #pragma unroll
            for (int ri = 0; ri < 4; ++ri) {
                int m = mBase + wr * 64 + rg * 16 + lg * 4 + ri;
                int t = m >> 1, b = m & 1;
                float val = acc[rg][cg][ri] + bs;
                if (which == 0) val *= QSCALE;
                dst[((size_t)(b * NHEAD + h) * T_LEN + t) * HDIM + dd] = f2bf(val);
            }
        }
    }
}

// ---------------------------------------------------------------------------
// Kernel 2: flash attention, swapped-QK^T bf16 MFMA, exp2-domain softmax,
// defer-max (THR=8), cvt_pk P-packing, gload_lds+XOR-swizzled K.
// grid: (32, 32), block 256
// ---------------------------------------------------------------------------
__global__ __launch_bounds__(256) void flash_kernel(
    const short* __restrict__ qb, const short* __restrict__ kbuf,
    const short* __restrict__ vbuf, short* __restrict__ h1,
    short* __restrict__ h2, float* __restrict__ mlws)
{
    const int qt = blockIdx.x;
    const int hb = blockIdx.y;

    __shared__ short Kst[64][64];   // [s][d], XOR-swizzled 16B units (linear dest)
    __shared__ short VT [64][64];   // [d][s], XOR-swizzled bytes
    __shared__ short Pst[64][72];   // [q][s], wave-private 16-row slices

    const int tid  = threadIdx.x;
    const int lane = tid & 63;
    const int w    = tid >> 6;
    const int lr   = lane & 15, lg = lane >> 4;

    bf16x8 qa0, qa1;
    {
        const short* qsrc = qb + ((size_t)hb * T_LEN + qt * 64 + w * 16 + lr) * HDIM;
        qa0 = *(const bf16x8*)(qsrc + lg * 8);
        qa1 = *(const bf16x8*)(qsrc + 32 + lg * 8);
    }
    // K staging source: inverse-swizzled per-lane global col (rule 21)
    const int krow  = (lane >> 3);                  // row within 8-row stripe
    const int kc16  = (lane & 7) ^ krow;            // swizzled 16B col
    // Kst fragment read offsets (swizzled): row s, col16 = (ks*4+lg)^(lr&7)
    const int rb0 = ((0 + lg) ^ (lr & 7)) * 16;
    const int rb1 = ((4 + lg) ^ (lr & 7)) * 16;

    float m_r = -INFINITY, l_r = 0.f;     // for q = lr (replicated over lg)
    f32x4 o_acc[4] = {};                  // [dsub]; reg ri -> q = lg*4+ri

    for (int st = 0; st < T_LEN / 64; ++st) {
        __syncthreads();
        // stage K via async gload: 2 x 1KB per wave, linear dest
        #pragma unroll
        for (int it = 0; it < 2; ++it) {
            int r = (w * 2 + it) * 8 + krow;
            gload16(kbuf + ((size_t)hb * T_LEN + st * 64 + r) * HDIM + kc16 * 8,
                    (char*)Kst + (w * 2 + it) * 1024);
        }
        // stage V transposed into swizzled VT
        {
            int dc = tid & 7, s0 = (tid >> 3) * 2;
            const short* v0 = vbuf + ((size_t)hb * T_LEN + st * 64 + s0) * HDIM + dc * 8;
            bf16x8 va  = *(const bf16x8*)v0;
            bf16x8 vb2 = *(const bf16x8*)(v0 + HDIM);
            #pragma unroll
            for (int j = 0; j < 8; ++j) {
                int d = dc * 8 + j;
                unsigned pk = ((unsigned)(unsigned short)va[j]) |
                              (((unsigned)(unsigned short)vb2[j]) << 16);
                int byte = (d << 7) + (s0 << 1);
                byte ^= (((d & 7) ^ (d >> 3)) << 4);
                *(unsigned*)((char*)VT + byte) = pk;
            }
        }
        __syncthreads();

        // QK^T swapped: sc[sg] holds S[s = sg*16 + lg*4+ri][q = lr]
        f32x4 sc[4] = {};
        #pragma unroll
        for (int sg = 0; sg < 4; ++sg) {
            const char* krowp = (const char*)Kst + (sg * 16 + lr) * 128;
            bf16x8 kf0 = *(const bf16x8*)(krowp + rb0);
            bf16x8 kf1 = *(const bf16x8*)(krowp + rb1);
            sc[sg] = MFMA16(kf0, qa0, sc[sg]);
            sc[sg] = MFMA16(kf1, qa1, sc[sg]);
        }

        // online softmax (exp2 domain) with defer-max
        float mx = sc[0][0];
        #pragma unroll
        for (int sg = 0; sg < 4; ++sg)
            #pragma unroll
            for (int ri = 0; ri < 4; ++ri)
                mx = fmaxf(mx, sc[sg][ri]);
        mx = fmaxf(mx, __shfl_xor(mx, 16));
        mx = fmaxf(mx, __shfl_xor(mx, 32));
        if (__any(mx - m_r > 8.0f)) {         // rescale only when max grew a lot
            float mnew = fmaxf(m_r, mx);
            float scl  = exp2f(m_r - mnew);
            l_r *= scl;
            m_r = mnew;
            float sclq[4];
            #pragma unroll
            for (int ri = 0; ri < 4; ++ri) sclq[ri] = __shfl(scl, lg * 20 + ri);
            #pragma unroll
            for (int dsub = 0; dsub < 4; ++dsub)
                #pragma unroll
                for (int ri = 0; ri < 4; ++ri)
                    o_acc[dsub][ri] *= sclq[ri];
        }
        float p[4][4], psum = 0.f;
        #pragma unroll
        for (int sg = 0; sg < 4; ++sg)
            #pragma unroll
            for (int ri = 0; ri < 4; ++ri) {
                p[sg][ri] = exp2f(sc[sg][ri] - m_r);   // bounded by 2^8
                psum += p[sg][ri];
            }
        psum += __shfl_xor(psum, 16);
        psum += __shfl_xor(psum, 32);
        l_r += psum;

        // P -> bf16 via cvt_pk -> wave-private LDS rows
        #pragma unroll
        for (int sg = 0; sg < 4; ++sg) {
            uint2 pk;
            pk.x = cvtpk(p[sg][0], p[sg][1]);
            pk.y = cvtpk(p[sg][2], p[sg][3]);
            *(uint2*)&Pst[w * 16 + lr][sg * 16 + lg * 4] = pk;
        }

        // PV: O[q][d] += P[q][s] * V[s][d]
        #pragma unroll
        for (int ks = 0; ks < 2; ++ks) {
            bf16x8 pa = *(const bf16x8*)&Pst[w * 16 + lr][ks * 32 + lg * 8];
            #pragma unroll
            for (int dsub = 0; dsub < 4; ++dsub) {
                int d = dsub * 16 + lr;
                int byte = (d << 7) + ((ks * 32 + lg * 8) << 1);
                byte ^= (((d & 7) ^ (d >> 3)) << 4);
                bf16x8 vf = *(const bf16x8*)((char*)VT + byte);
                o_acc[dsub] = MFMA16(pa, vf, o_acc[dsub]);
            }
        }
    }

    float inv = 1.0f / l_r;
    float invq[4];
    #pragma unroll
    for (int ri = 0; ri < 4; ++ri) invq[ri] = __shfl(inv, lg * 20 + ri);
    #pragma unroll
    for (int ri = 0; ri < 4; ++ri) {
        int row = qt * 64 + w * 16 + lg * 4 + ri;
        #pragma unroll
        for (int dsub = 0; dsub < 4; ++dsub) {
            float x = o_acc[dsub][ri] * invq[ri];
            size_t idx = ((size_t)hb * T_LEN + row) * HDIM + dsub * 16 + lr;
            short a = f2bf(x);
            h1[idx] = a;
            h2[idx] = f2bf(x - bf2f(a));
        }
    }
    if (lg == 0) {
        int row = qt * 64 + w * 16 + lr;
        mlws[(size_t)hb * T_LEN + row] = m_r + __log2f(l_r);   // fused m + log2(l)
    }
}

// ---------------------------------------------------------------------------
// Kernel 3: attn_avg. p = exp2(sc - ml), ml = m + log2(l). 4 heads per
// barrier-pair via gload_lds. grid: (32 st, 32 qt, 2 b), block 256
// ---------------------------------------------------------------------------
__global__ __launch_bounds__(256) void avg_kernel(
    const short* __restrict__ qbuf, const short* __restrict__ kbuf,
    const float* __restrict__ mlws, float* __restrict__ attn_avg)
{
    const int st = blockIdx.x;
    const int qt = blockIdx.y;
    const int b  = blockIdx.z;

    __shared__ short K4[4][64][64];   // 32 KB, linear for gload_lds

    const int tid  = threadIdx.x;
    const int lane = tid & 63;
    const int w    = tid >> 6;
    const int lr   = lane & 15, lg = lane >> 4;

    f32x4 acc[4] = {};

    for (int rnd = 0; rnd < 4; ++rnd) {
        __syncthreads();
        #pragma unroll
        for (int hh = 0; hh < 4; ++hh) {
            int hb = b * NHEAD + rnd * 4 + hh;
            #pragma unroll
            for (int j = 0; j < 2; ++j) {
                int row = j * 32 + (tid >> 3);
                int col = (tid & 7) * 8;
                gload16(kbuf + ((size_t)hb * T_LEN + st * 64 + row) * HDIM + col,
                        (char*)K4[hh] + j * 4096 + w * 1024);
            }
        }
        __syncthreads();
        #pragma unroll
        for (int hh = 0; hh < 4; ++hh) {
            int hb = b * NHEAD + rnd * 4 + hh;
            const short* qsrc = qbuf + ((size_t)hb * T_LEN + qt * 64 + w * 16 + lr) * HDIM;
            bf16x8 qa0 = *(const bf16x8*)(qsrc + lg * 8);
            bf16x8 qa1 = *(const bf16x8*)(qsrc + 32 + lg * 8);

            f32x4 sc[4] = {};
            #pragma unroll
            for (int sg = 0; sg < 4; ++sg) {
                bf16x8 kf0 = *(const bf16x8*)&K4[hh][sg * 16 + lr][lg * 8];
                bf16x8 kf1 = *(const bf16x8*)&K4[hh][sg * 16 + lr][32 + lg * 8];
                sc[sg] = MFMA16(qa0, kf0, sc[sg]);
                sc[sg] = MFMA16(qa1, kf1, sc[sg]);
            }

            #pragma unroll
            for (int ri = 0; ri < 4; ++ri) {
                int row = qt * 64 + w * 16 + lg * 4 + ri;
                float ml = mlws[(size_t)hb * T_LEN + row];
                #pragma unroll
                for (int sg = 0; sg < 4; ++sg)
                    acc[sg][ri] += exp2f(sc[sg][ri] - ml);
            }
        }
    }

    const float invH = 1.0f / (float)NHEAD;
    #pragma unroll
    for (int ri = 0; ri < 4; ++ri) {
        int row = qt * 64 + w * 16 + lg * 4 + ri;
        #pragma unroll
        for (int sg = 0; sg < 4; ++sg)
            attn_avg[((size_t)b * T_LEN + row) * T_LEN + st * 64 + sg * 16 + lr] =
                acc[sg][ri] * invH;
    }
}

// ---------------------------------------------------------------------------
// Kernel 4: out-projection, bf16 MFMA, split-ho compensation.
// grid: (32, 8), block 256
// ---------------------------------------------------------------------------
__global__ __launch_bounds__(256) void outproj_gemm(
    const short* __restrict__ h1, const short* __restrict__ h2,
    const short* __restrict__ Wob, const float* __restrict__ bo,
    float* __restrict__ out)
{
    const int mBase = blockIdx.x * 128;
    const int nBase = blockIdx.y * 128;

    __shared__ short A1st[128][64];
    __shared__ short A2st[128][64];
    __shared__ short Bst [128][64];

    const int tid  = threadIdx.x;
    const int lane = tid & 63;
    const int w    = tid >> 6;
    const int wr   = w >> 1, wc = w & 1;
    const int lr   = lane & 15, lg = lane >> 4;
    const int srow = tid >> 3;
    const int scol = (tid & 7) * 8;

    f32x4 acc[4][4] = {};

    for (int kb = 0; kb < EMB; kb += 64) {
        const int h = kb >> 6;
        __syncthreads();
        #pragma unroll
        for (int j = 0; j < 4; ++j) {
            int m = mBase + j * 32 + srow;
            int t = m >> 1, b = m & 1;
            size_t aoff = ((size_t)(b * NHEAD + h) * T_LEN + t) * HDIM + scol;
            gload16(h1 + aoff, (char*)A1st + j * 4096 + w * 1024);
            gload16(h2 + aoff, (char*)A2st + j * 4096 + w * 1024);
            gload16(Wob + (size_t)(nBase + j * 32 + srow) * EMB + kb + scol,
                    (char*)Bst + j * 4096 + w * 1024);
        }
        __syncthreads();
        #pragma unroll
        for (int ks = 0; ks < 2; ++ks) {
            bf16x8 a1[4], a2[4], bfr[4];
            #pragma unroll
            for (int rg = 0; rg < 4; ++rg) {
                a1[rg] = *(const bf16x8*)&A1st[wr * 64 + rg * 16 + lr][ks * 32 + lg * 8];
                a2[rg] = *(const bf16x8*)&A2st[wr * 64 + rg * 16 + lr][ks * 32 + lg * 8];
            }
            #pragma unroll
            for (int cg = 0; cg < 4; ++cg)
                bfr[cg] = *(const bf16x8*)&Bst[wc * 64 + cg * 16 + lr][ks * 32 + lg * 8];
            #pragma unroll
            for (int rg = 0; rg < 4; ++rg)
                #pragma unroll
                for (int cg = 0; cg < 4; ++cg) {
                    acc[rg][cg] = MFMA16(a1[rg], bfr[cg], acc[rg][cg]);
                    acc[rg][cg] = MFMA16(a2[rg], bfr[cg], acc[rg][cg]);
                }
        }
    }

    #pragma unroll
    for (int rg = 0; rg < 4; ++rg) {
        #pragma unroll
        for (int cg = 0; cg < 4; ++cg) {
            int n = nBase + wc * 64 + cg * 16 + lr;
            float bs = bo[n];
            #pragma unroll
            for (int ri = 0; ri < 4; ++ri) {
                int m = mBase + wr * 64 + rg * 16 + lg * 4 + ri;
                out[(size_t)m * EMB + n] = acc[rg][cg][ri] + bs;
            }
        }
    }
}

// ---------------------------------------------------------------------------
extern "C" void kernel_launch(void* const* d_in, const int* in_sizes, int n_in,
                              void* d_out, int out_size, void* d_ws, size_t ws_size,
                              hipStream_t stream)
{
    const float* query = (const float*)d_in[0];
    const float* key   = (const float*)d_in[1];
    const float* value = (const float*)d_in[2];
    const float* ipw   = (const float*)d_in[3];
    const float* ipb   = (const float*)d_in[4];
    const float* opw   = (const float*)d_in[5];
    const float* opb   = (const float*)d_in[6];

    short* qb  = (short*)d_ws;
    short* kb  = qb + HEADBUF;
    short* vb  = kb + HEADBUF;
    short* h1  = vb + HEADBUF;                     // inproj: Xq_bf
    short* h2  = h1 + HEADBUF;                     // inproj: Xk_bf
    short* xvb = h2 + HEADBUF;                     // inproj: Xv_bf
    short* wbf = xvb + HEADBUF;                    // 3*EMB*EMB
    short* wob = wbf + (size_t)3 * EMB * EMB;      // EMB*EMB
    float* mlws = (float*)(wob + (size_t)EMB * EMB);  // BH*T_LEN

    float* out      = (float*)d_out;
    float* attn_avg = out + (size_t)MROWS * EMB;

    tobf16_kernel<<<8192, 256, 0, stream>>>(query, key, value, ipw, opw, h1);
    inproj_gemm  <<<dim3(MROWS / 128, 3 * EMB / 128), 256, 0, stream>>>(
        h1, h2, xvb, wbf, ipb, qb, kb, vb);
    flash_kernel <<<dim3(T_LEN / 64, BH),             256, 0, stream>>>(
        qb, kb, vb, h1, h2, mlws);
    avg_kernel   <<<dim3(T_LEN / 64, T_LEN / 64, BATCH), 256, 0, stream>>>(
        qb, kb, mlws, attn_avg);
    outproj_gemm <<<dim3(MROWS / 128, EMB / 128),     256, 0, stream>>>(
        h1, h2, wob, opb, out);
}